// Round 1
// baseline (920.022 us; speedup 1.0000x reference)
//
#include <hip/hip_runtime.h>
#include <hip/hip_bf16.h>

using bf16 = __hip_bfloat16;
typedef float f32x4 __attribute__((ext_vector_type(4)));
typedef short bf16x8 __attribute__((ext_vector_type(8)));

#define DD 768
#define SS 1024
#define HH 12
#define DFF 3072

__device__ __forceinline__ float bf2f(bf16 v) { return __bfloat162float(v); }
__device__ __forceinline__ bf16 f2bf(float v) { return __float2bfloat16(v); }

// ---------- transpose + cast f32 -> bf16 : dst[c][r] = src[r][c] ----------
__global__ __launch_bounds__(256) void transpose_cast_kernel(
    const float* __restrict__ src, bf16* __restrict__ dst,
    int R, int C, long sstride, long dstride)
{
  __shared__ float tile[32][33];
  const int c0 = blockIdx.x * 32, r0 = blockIdx.y * 32;
  const float* s = src + (long)blockIdx.z * sstride;
  bf16* d = dst + (long)blockIdx.z * dstride;
  for (int i = threadIdx.y; i < 32; i += 8)
    tile[i][threadIdx.x] = s[(long)(r0 + i) * C + c0 + threadIdx.x];
  __syncthreads();
  for (int i = threadIdx.y; i < 32; i += 8)
    d[(long)(c0 + i) * R + r0 + threadIdx.x] = f2bf(tile[threadIdx.x][i]);
}

// ---------- pooled = mean over S ----------
__global__ __launch_bounds__(256) void pool_kernel(
    const float* __restrict__ x, float* __restrict__ pooled)
{
  const int idx = blockIdx.x * 256 + threadIdx.x;   // 0..3071  (B*D)
  const int b = idx / DD, d = idx % DD;
  const float* p = x + (long)b * SS * DD + d;
  float s = 0.f;
  for (int t = 0; t < SS; t++) s += p[(long)t * DD];
  pooled[idx] = s * (1.f / SS);
}

// ---------- routing bias: tl = pooled@Wt + bt ; rbias[b][e] = tl[b][e&1] ----------
__global__ __launch_bounds__(256) void route_kernel(
    const float* __restrict__ pooled, const float* __restrict__ Wt,
    const float* __restrict__ bt, float* __restrict__ rbias)
{
  __shared__ float tl[8];
  const int pair = threadIdx.x >> 5, l = threadIdx.x & 31;
  const int b = pair >> 1, j = pair & 1;
  float s = 0.f;
  for (int i = l; i < DD; i += 32) s += pooled[b * DD + i] * Wt[i * 2 + j];
  #pragma unroll
  for (int o = 1; o < 32; o <<= 1) s += __shfl_xor(s, o, 64);
  if (l == 0) tl[pair] = s + bt[j];
  __syncthreads();
  if (threadIdx.x < 16) {
    const int bb = threadIdx.x >> 2, e = threadIdx.x & 3;
    rbias[threadIdx.x] = tl[bb * 2 + (e & 1)];
  }
}

// ---------- layernorm row -> bf16 (wave per row) ----------
__global__ __launch_bounds__(256) void ln_kernel(
    const float* __restrict__ x, const float* __restrict__ g,
    const float* __restrict__ b, bf16* __restrict__ out)
{
  const int row = blockIdx.x * 4 + (threadIdx.x >> 6);
  const int lane = threadIdx.x & 63;
  const float* xr = x + (long)row * DD;
  float v[12];
  float s = 0.f;
  #pragma unroll
  for (int i = 0; i < 12; i++) { v[i] = xr[lane + i * 64]; s += v[i]; }
  #pragma unroll
  for (int o = 1; o < 64; o <<= 1) s += __shfl_xor(s, o, 64);
  const float mu = s * (1.f / DD);
  float vs = 0.f;
  #pragma unroll
  for (int i = 0; i < 12; i++) { const float d = v[i] - mu; vs += d * d; }
  #pragma unroll
  for (int o = 1; o < 64; o <<= 1) vs += __shfl_xor(vs, o, 64);
  const float rstd = rsqrtf(vs * (1.f / DD) + 1e-5f);
  bf16* orow = out + (long)row * DD;
  #pragma unroll
  for (int i = 0; i < 12; i++) {
    const int d = lane + i * 64;
    orow[d] = f2bf((v[i] - mu) * rstd * g[d] + b[d]);
  }
}

__device__ __forceinline__ float gelu_tanh(float x) {
  const float x3 = x * x * x;
  const float t = tanhf(0.7978845608028654f * (x + 0.044715f * x3));
  return 0.5f * x * (1.f + t);
}

// ---------- 128x128 bf16 MFMA GEMM, A[M][K] x Bt[N][K] ----------
// MODE 0: C=bf16 store   1: Cf = aux1 + acc (residual)   2: Cbf = gelu(acc+aux1[col])
// MODE 3: Cf += aux2[row*4] * (acc + aux1[col])
template <int MODE>
__global__ __launch_bounds__(256) void gemm128_kernel(
    const bf16* __restrict__ A, const bf16* __restrict__ Bt,
    bf16* __restrict__ Cbf, float* __restrict__ Cf,
    int M, int N, int K,
    const float* __restrict__ aux1, const float* __restrict__ aux2)
{
  __shared__ __align__(16) bf16 As[128 * 32];
  __shared__ __align__(16) bf16 Bs[128 * 32];
  const int m0 = blockIdx.y * 128, n0 = blockIdx.x * 128;
  const int tid = threadIdx.x;
  const int lane = tid & 63, wave = tid >> 6;
  const int wr = wave >> 1, wc = wave & 1;
  const int lrow = lane & 15, lk = lane >> 4;

  f32x4 acc[4][4] = {};

  for (int k0 = 0; k0 < K; k0 += 32) {
    __syncthreads();
    #pragma unroll
    for (int u = 0; u < 2; u++) {
      const int c = tid + u * 256;
      const int row = c >> 2, cb = (c & 3) * 8;
      *(f32x4*)(&As[row * 32 + cb]) =
          *(const f32x4*)(&A[(long)(m0 + row) * K + k0 + cb]);
      *(f32x4*)(&Bs[row * 32 + cb]) =
          *(const f32x4*)(&Bt[(long)(n0 + row) * K + k0 + cb]);
    }
    __syncthreads();
    bf16x8 af[4], bfr[4];
    #pragma unroll
    for (int i = 0; i < 4; i++) {
      af[i]  = *(const bf16x8*)(&As[(wr * 64 + i * 16 + lrow) * 32 + lk * 8]);
      bfr[i] = *(const bf16x8*)(&Bs[(wc * 64 + i * 16 + lrow) * 32 + lk * 8]);
    }
    #pragma unroll
    for (int i = 0; i < 4; i++)
      #pragma unroll
      for (int j = 0; j < 4; j++)
        acc[i][j] = __builtin_amdgcn_mfma_f32_16x16x32_bf16(af[i], bfr[j], acc[i][j], 0, 0, 0);
  }

  #pragma unroll
  for (int i = 0; i < 4; i++) {
    const int rb = m0 + wr * 64 + i * 16 + lk * 4;
    #pragma unroll
    for (int j = 0; j < 4; j++) {
      const int col = n0 + wc * 64 + j * 16 + lrow;
      #pragma unroll
      for (int r = 0; r < 4; r++) {
        const long idx = (long)(rb + r) * N + col;
        const float v = acc[i][j][r];
        if (MODE == 0) {
          Cbf[idx] = f2bf(v);
        } else if (MODE == 1) {
          Cf[idx] = aux1[idx] + v;
        } else if (MODE == 2) {
          Cbf[idx] = f2bf(gelu_tanh(v + aux1[col]));
        } else {
          const float gg = aux2[(long)(rb + r) * 4];
          Cf[idx] += gg * (v + aux1[col]);
        }
      }
    }
  }
}

// ---------- flash attention, fp32 LDS tiles, 64 q-rows per block ----------
__global__ __launch_bounds__(256) void attn_kernel(
    const bf16* __restrict__ qkv, bf16* __restrict__ ctx)
{
  __shared__ __align__(16) float Qs[64][68];
  __shared__ __align__(16) float Ks[64][68];
  __shared__ __align__(16) float Vs[64][68];
  __shared__ __align__(16) unsigned short Ps[64][72];

  const int qt = blockIdx.x;      // 0..15
  const int bh = blockIdx.y;      // 0..47
  const int b = bh / HH, h = bh % HH;
  const int tid = threadIdx.x;
  const int tx = tid & 15, ty = tid >> 4;

  const long rowq0 = (long)(b * SS + qt * 64);
  const long qbase = rowq0 * 2304 + h * 64;
  const long kbase = (long)(b * SS) * 2304 + 768 + h * 64;
  const long vbase = (long)(b * SS) * 2304 + 1536 + h * 64;

  for (int idx = tid; idx < 64 * 64; idx += 256) {
    const int r = idx >> 6, c = idx & 63;
    Qs[r][c] = bf2f(qkv[qbase + (long)r * 2304 + c]) * 0.125f;  // fold 1/sqrt(64)
  }

  float m_run[4], l_run[4];
  f32x4 oacc[4];
  #pragma unroll
  for (int i = 0; i < 4; i++) {
    m_run[i] = -1e30f; l_run[i] = 0.f;
    oacc[i] = (f32x4){0.f, 0.f, 0.f, 0.f};
  }

  for (int kt = 0; kt < 16; kt++) {
    __syncthreads();
    for (int idx = tid; idx < 64 * 64; idx += 256) {
      const int r = idx >> 6, c = idx & 63;
      Ks[r][c] = bf2f(qkv[kbase + (long)(kt * 64 + r) * 2304 + c]);
      Vs[r][c] = bf2f(qkv[vbase + (long)(kt * 64 + r) * 2304 + c]);
    }
    __syncthreads();

    float s[4][4] = {};
    for (int kk = 0; kk < 64; kk += 4) {
      f32x4 qv[4], kv[4];
      #pragma unroll
      for (int i = 0; i < 4; i++) qv[i] = *(const f32x4*)(&Qs[ty + 16 * i][kk]);
      #pragma unroll
      for (int j = 0; j < 4; j++) kv[j] = *(const f32x4*)(&Ks[tx + 16 * j][kk]);
      #pragma unroll
      for (int i = 0; i < 4; i++)
        #pragma unroll
        for (int j = 0; j < 4; j++)
          s[i][j] += qv[i].x * kv[j].x + qv[i].y * kv[j].y +
                     qv[i].z * kv[j].z + qv[i].w * kv[j].w;
    }

    #pragma unroll
    for (int i = 0; i < 4; i++) {
      float mt = fmaxf(fmaxf(s[i][0], s[i][1]), fmaxf(s[i][2], s[i][3]));
      #pragma unroll
      for (int o = 1; o < 16; o <<= 1) mt = fmaxf(mt, __shfl_xor(mt, o, 64));
      const float mn = fmaxf(m_run[i], mt);
      const float sc = __expf(m_run[i] - mn);
      m_run[i] = mn;
      float rs = 0.f;
      #pragma unroll
      for (int j = 0; j < 4; j++) {
        const float p = __expf(s[i][j] - mn);
        rs += p;
        bf16 pb = f2bf(p);
        Ps[ty + 16 * i][tx + 16 * j] = reinterpret_cast<unsigned short&>(pb);
      }
      #pragma unroll
      for (int o = 1; o < 16; o <<= 1) rs += __shfl_xor(rs, o, 64);
      l_run[i] = l_run[i] * sc + rs;
      oacc[i] *= sc;
    }
    __syncthreads();

    for (int j4 = 0; j4 < 64; j4 += 4) {
      f32x4 vv[4];
      #pragma unroll
      for (int jj = 0; jj < 4; jj++) vv[jj] = *(const f32x4*)(&Vs[j4 + jj][tx * 4]);
      #pragma unroll
      for (int i = 0; i < 4; i++) {
        const ushort4 pu = *(const ushort4*)(&Ps[ty + 16 * i][j4]);
        const float p0 = __uint_as_float((unsigned)pu.x << 16);
        const float p1 = __uint_as_float((unsigned)pu.y << 16);
        const float p2 = __uint_as_float((unsigned)pu.z << 16);
        const float p3 = __uint_as_float((unsigned)pu.w << 16);
        oacc[i] += p0 * vv[0] + p1 * vv[1] + p2 * vv[2] + p3 * vv[3];
      }
    }
  }

  #pragma unroll
  for (int i = 0; i < 4; i++) {
    const float inv = 1.f / l_run[i];
    const long orow = (rowq0 + ty + 16 * i) * DD + h * 64 + tx * 4;
    #pragma unroll
    for (int dd = 0; dd < 4; dd++)
      ctx[orow + dd] = f2bf(oacc[i][dd] * inv);
  }
}

// ---------- gate: exact-fp32 LN2 + logits + top2 softmax ----------
__global__ __launch_bounds__(256) void gate_kernel(
    const float* __restrict__ x2, const float* __restrict__ g,
    const float* __restrict__ bln, const float* __restrict__ Wg,
    const float* __restrict__ rbias, float* __restrict__ gates)
{
  const int t = blockIdx.x * 4 + (threadIdx.x >> 6);
  const int lane = threadIdx.x & 63;
  const int b = t >> 10;
  const float* xr = x2 + (long)t * DD;
  float v[12];
  float s = 0.f;
  #pragma unroll
  for (int i = 0; i < 12; i++) { v[i] = xr[lane + i * 64]; s += v[i]; }
  #pragma unroll
  for (int o = 1; o < 64; o <<= 1) s += __shfl_xor(s, o, 64);
  const float mu = s * (1.f / DD);
  float vs = 0.f;
  #pragma unroll
  for (int i = 0; i < 12; i++) { const float d = v[i] - mu; vs += d * d; }
  #pragma unroll
  for (int o = 1; o < 64; o <<= 1) vs += __shfl_xor(vs, o, 64);
  const float rstd = rsqrtf(vs * (1.f / DD) + 1e-5f);
  float a0 = 0.f, a1 = 0.f, a2 = 0.f, a3 = 0.f;
  #pragma unroll
  for (int i = 0; i < 12; i++) {
    const int d = lane + i * 64;
    const float hv = (v[i] - mu) * rstd * g[d] + bln[d];
    const f32x4 w = *(const f32x4*)(&Wg[d * 4]);
    a0 += hv * w.x; a1 += hv * w.y; a2 += hv * w.z; a3 += hv * w.w;
  }
  #pragma unroll
  for (int o = 1; o < 64; o <<= 1) {
    a0 += __shfl_xor(a0, o, 64); a1 += __shfl_xor(a1, o, 64);
    a2 += __shfl_xor(a2, o, 64); a3 += __shfl_xor(a3, o, 64);
  }
  if (lane == 0) {
    float lg[4] = { a0 + rbias[b * 4 + 0], a1 + rbias[b * 4 + 1],
                    a2 + rbias[b * 4 + 2], a3 + rbias[b * 4 + 3] };
    int i1 = 0;
    #pragma unroll
    for (int e = 1; e < 4; e++) if (lg[e] > lg[i1]) i1 = e;
    int i2 = -1;
    #pragma unroll
    for (int e = 0; e < 4; e++) if (e != i1 && (i2 < 0 || lg[e] > lg[i2])) i2 = e;
    const float e2 = __expf(lg[i2] - lg[i1]);
    const float den = 1.f + e2;
    float og[4] = {0.f, 0.f, 0.f, 0.f};
    og[i1] = 1.f / den;
    og[i2] = e2 / den;
    *(f32x4*)(&gates[t * 4]) = (f32x4){og[0], og[1], og[2], og[3]};
  }
}

__global__ __launch_bounds__(256) void copy4_kernel(
    const float* __restrict__ src, float* __restrict__ dst)
{
  const long i = ((long)blockIdx.x * 256 + threadIdx.x) * 4;
  *(f32x4*)(&dst[i]) = *(const f32x4*)(&src[i]);
}

extern "C" void kernel_launch(void* const* d_in, const int* in_sizes, int n_in,
                              void* d_out, int out_size, void* d_ws, size_t ws_size,
                              hipStream_t stream)
{
  (void)in_sizes; (void)n_in; (void)out_size; (void)ws_size;
  const float* x    = (const float*)d_in[0];
  const float* ln1g = (const float*)d_in[1];
  const float* ln1b = (const float*)d_in[2];
  const float* Wq   = (const float*)d_in[3];
  const float* Wk   = (const float*)d_in[4];
  const float* Wv   = (const float*)d_in[5];
  const float* Wo   = (const float*)d_in[6];
  const float* Wt   = (const float*)d_in[7];
  const float* bt   = (const float*)d_in[8];
  const float* ln2g = (const float*)d_in[9];
  const float* ln2b = (const float*)d_in[10];
  const float* Wg   = (const float*)d_in[11];
  const float* W1   = (const float*)d_in[12];
  const float* b1   = (const float*)d_in[13];
  const float* W2   = (const float*)d_in[14];
  const float* b2   = (const float*)d_in[15];
  float* out = (float*)d_out;

  char* ws = (char*)d_ws;
  bf16*  wqkv_t = (bf16*)(ws + 0);          // [2304][768] bf16
  bf16*  wo_t   = (bf16*)(ws + 3538944);    // [768][768]
  bf16*  w1t    = (bf16*)(ws + 4718592);    // [4][3072][768]
  bf16*  w2t    = (bf16*)(ws + 23592960);   // [4][768][3072]
  float* pooled = (float*)(ws + 42467328);  // [4][768]
  float* rbias  = (float*)(ws + 42479616);  // [4][4]
  bf16*  h1     = (bf16*)(ws + 42479872);   // [4096][768]
  bf16*  qkv    = (bf16*)(ws + 48771328);   // [4096][2304]
  bf16*  ctx    = (bf16*)(ws + 67645696);   // [4096][768]
  float* x2     = (float*)(ws + 73937152);  // [4096][768] f32
  bf16*  h2     = (bf16*)(ws + 86520064);   // [4096][768]
  float* gates  = (float*)(ws + 92811520);  // [4096][4] f32
  bf16*  hid    = qkv;  // alias: qkv+ctx (25,165,824 B) dead by MoE time

  const dim3 tb(32, 8);
  transpose_cast_kernel<<<dim3(24, 24, 1), tb, 0, stream>>>(Wq, wqkv_t,           768, 768, 0, 0);
  transpose_cast_kernel<<<dim3(24, 24, 1), tb, 0, stream>>>(Wk, wqkv_t + 589824,  768, 768, 0, 0);
  transpose_cast_kernel<<<dim3(24, 24, 1), tb, 0, stream>>>(Wv, wqkv_t + 1179648, 768, 768, 0, 0);
  transpose_cast_kernel<<<dim3(24, 24, 1), tb, 0, stream>>>(Wo, wo_t,             768, 768, 0, 0);
  transpose_cast_kernel<<<dim3(96, 24, 4), tb, 0, stream>>>(W1, w1t, 768, 3072, 2359296, 2359296);
  transpose_cast_kernel<<<dim3(24, 96, 4), tb, 0, stream>>>(W2, w2t, 3072, 768, 2359296, 2359296);

  pool_kernel<<<12, 256, 0, stream>>>(x, pooled);
  route_kernel<<<1, 256, 0, stream>>>(pooled, Wt, bt, rbias);
  ln_kernel<<<1024, 256, 0, stream>>>(x, ln1g, ln1b, h1);

  gemm128_kernel<0><<<dim3(18, 32), 256, 0, stream>>>(h1, wqkv_t, qkv, nullptr,
                                                      4096, 2304, 768, nullptr, nullptr);
  attn_kernel<<<dim3(16, 48), 256, 0, stream>>>(qkv, ctx);
  gemm128_kernel<1><<<dim3(6, 32), 256, 0, stream>>>(ctx, wo_t, nullptr, x2,
                                                     4096, 768, 768, x, nullptr);
  ln_kernel<<<1024, 256, 0, stream>>>(x2, ln2g, ln2b, h2);
  gate_kernel<<<1024, 256, 0, stream>>>(x2, ln2g, ln2b, Wg, rbias, gates);
  copy4_kernel<<<3072, 256, 0, stream>>>(x2, out);

  for (int e = 0; e < 4; e++) {
    gemm128_kernel<2><<<dim3(24, 32), 256, 0, stream>>>(h2, w1t + (long)e * 2359296, hid, nullptr,
                                                        4096, 3072, 768, b1 + e * 3072, nullptr);
    gemm128_kernel<3><<<dim3(6, 32), 256, 0, stream>>>(hid, w2t + (long)e * 2359296, nullptr, out,
                                                       4096, 768, 3072, b2 + e * 768, gates + e);
  }
}

// Round 2
// 699.657 us; speedup vs baseline: 1.3150x; 1.3150x over previous
//
#include <hip/hip_runtime.h>
#include <hip/hip_bf16.h>

using bf16 = __hip_bfloat16;
typedef float f32x4 __attribute__((ext_vector_type(4)));
typedef short bf16x8 __attribute__((ext_vector_type(8)));

#define DD 768
#define SS 1024
#define HH 12
#define DFF 3072

__device__ __forceinline__ float bf2f(bf16 v) { return __bfloat162float(v); }
__device__ __forceinline__ bf16 f2bf(float v) { return __float2bfloat16(v); }
__device__ __forceinline__ float sb2f(short u) {
  return __uint_as_float(((unsigned)(unsigned short)u) << 16);
}
__device__ __forceinline__ short f2sb(float f) {
  bf16 b = f2bf(f);
  return reinterpret_cast<short&>(b);
}

// async global->LDS, 16B per lane; lds base must be wave-uniform
__device__ __forceinline__ void gld16(const void* g, void* l) {
  __builtin_amdgcn_global_load_lds(
      (const __attribute__((address_space(1))) void*)g,
      (__attribute__((address_space(3))) void*)l, 16, 0, 0);
}

// ---------- transpose + cast f32 -> bf16 : dst[c][r] = src[r][c] ----------
__global__ __launch_bounds__(256) void transpose_cast_kernel(
    const float* __restrict__ src, bf16* __restrict__ dst,
    int R, int C, long sstride, long dstride)
{
  __shared__ float tile[32][33];
  const int c0 = blockIdx.x * 32, r0 = blockIdx.y * 32;
  const float* s = src + (long)blockIdx.z * sstride;
  bf16* d = dst + (long)blockIdx.z * dstride;
  for (int i = threadIdx.y; i < 32; i += 8)
    tile[i][threadIdx.x] = s[(long)(r0 + i) * C + c0 + threadIdx.x];
  __syncthreads();
  for (int i = threadIdx.y; i < 32; i += 8)
    d[(long)(c0 + i) * R + r0 + threadIdx.x] = f2bf(tile[threadIdx.x][i]);
}

// ---------- pooled = mean over S ----------
__global__ __launch_bounds__(256) void pool_kernel(
    const float* __restrict__ x, float* __restrict__ pooled)
{
  const int idx = blockIdx.x * 256 + threadIdx.x;   // 0..3071  (B*D)
  const int b = idx / DD, d = idx % DD;
  const float* p = x + (long)b * SS * DD + d;
  float s = 0.f;
  for (int t = 0; t < SS; t++) s += p[(long)t * DD];
  pooled[idx] = s * (1.f / SS);
}

// ---------- routing bias ----------
__global__ __launch_bounds__(256) void route_kernel(
    const float* __restrict__ pooled, const float* __restrict__ Wt,
    const float* __restrict__ bt, float* __restrict__ rbias)
{
  __shared__ float tl[8];
  const int pair = threadIdx.x >> 5, l = threadIdx.x & 31;
  const int b = pair >> 1, j = pair & 1;
  float s = 0.f;
  for (int i = l; i < DD; i += 32) s += pooled[b * DD + i] * Wt[i * 2 + j];
  #pragma unroll
  for (int o = 1; o < 32; o <<= 1) s += __shfl_xor(s, o, 64);
  if (l == 0) tl[pair] = s + bt[j];
  __syncthreads();
  if (threadIdx.x < 16) {
    const int bb = threadIdx.x >> 2, e = threadIdx.x & 3;
    rbias[threadIdx.x] = tl[bb * 2 + (e & 1)];
  }
}

// ---------- layernorm row -> bf16 (wave per row) ----------
__global__ __launch_bounds__(256) void ln_kernel(
    const float* __restrict__ x, const float* __restrict__ g,
    const float* __restrict__ b, bf16* __restrict__ out)
{
  const int row = blockIdx.x * 4 + (threadIdx.x >> 6);
  const int lane = threadIdx.x & 63;
  const float* xr = x + (long)row * DD;
  float v[12];
  float s = 0.f;
  #pragma unroll
  for (int i = 0; i < 12; i++) { v[i] = xr[lane + i * 64]; s += v[i]; }
  #pragma unroll
  for (int o = 1; o < 64; o <<= 1) s += __shfl_xor(s, o, 64);
  const float mu = s * (1.f / DD);
  float vs = 0.f;
  #pragma unroll
  for (int i = 0; i < 12; i++) { const float d = v[i] - mu; vs += d * d; }
  #pragma unroll
  for (int o = 1; o < 64; o <<= 1) vs += __shfl_xor(vs, o, 64);
  const float rstd = rsqrtf(vs * (1.f / DD) + 1e-5f);
  bf16* orow = out + (long)row * DD;
  #pragma unroll
  for (int i = 0; i < 12; i++) {
    const int d = lane + i * 64;
    orow[d] = f2bf((v[i] - mu) * rstd * g[d] + b[d]);
  }
}

__device__ __forceinline__ float gelu_tanh(float x) {
  const float x3 = x * x * x;
  const float t = tanhf(0.7978845608028654f * (x + 0.044715f * x3));
  return 0.5f * x * (1.f + t);
}

// ---------- 128x128 bf16 MFMA GEMM, A[M][K] x Bt[N][K], async LDS staging ----
// MODE 0: C=bf16   1: Cf = aux1 + acc   2: Cbf = gelu(acc+aux1[col])
// MODE 3: Cf += aux2[row*4] * (acc + aux1[col])
template <int MODE>
__global__ __launch_bounds__(256) void gemm128_kernel(
    const bf16* __restrict__ A, const bf16* __restrict__ Bt,
    bf16* __restrict__ Cbf, float* __restrict__ Cf,
    int M, int N, int K,
    const float* __restrict__ aux1, const float* __restrict__ aux2)
{
  __shared__ __align__(16) bf16 As[128 * 32];
  __shared__ __align__(16) bf16 Bs[128 * 32];
  const int m0 = blockIdx.y * 128, n0 = blockIdx.x * 128;
  const int tid = threadIdx.x;
  const int lane = tid & 63, wv = tid >> 6;
  const int wr = wv >> 1, wc = wv & 1;
  const int lrow = lane & 15, lk = lane >> 4;
  const int srow = lane >> 2, scb = (lane & 3) * 8;   // staging lane map

  f32x4 acc[4][4] = {};

  for (int k0 = 0; k0 < K; k0 += 32) {
    __syncthreads();
    #pragma unroll
    for (int u = 0; u < 2; u++) {
      const int rb = u * 64 + wv * 16;
      gld16(&A[(long)(m0 + rb + srow) * K + k0 + scb], &As[rb * 32]);
      gld16(&Bt[(long)(n0 + rb + srow) * K + k0 + scb], &Bs[rb * 32]);
    }
    __syncthreads();
    bf16x8 af[4], bfr[4];
    #pragma unroll
    for (int i = 0; i < 4; i++) {
      af[i]  = *(const bf16x8*)(&As[(wr * 64 + i * 16 + lrow) * 32 + lk * 8]);
      bfr[i] = *(const bf16x8*)(&Bs[(wc * 64 + i * 16 + lrow) * 32 + lk * 8]);
    }
    #pragma unroll
    for (int i = 0; i < 4; i++)
      #pragma unroll
      for (int j = 0; j < 4; j++)
        acc[i][j] = __builtin_amdgcn_mfma_f32_16x16x32_bf16(af[i], bfr[j], acc[i][j], 0, 0, 0);
  }

  #pragma unroll
  for (int i = 0; i < 4; i++) {
    const int rb = m0 + wr * 64 + i * 16 + lk * 4;
    #pragma unroll
    for (int j = 0; j < 4; j++) {
      const int col = n0 + wc * 64 + j * 16 + lrow;
      #pragma unroll
      for (int r = 0; r < 4; r++) {
        const long idx = (long)(rb + r) * N + col;
        const float v = acc[i][j][r];
        if (MODE == 0) {
          Cbf[idx] = f2bf(v);
        } else if (MODE == 1) {
          Cf[idx] = aux1[idx] + v;
        } else if (MODE == 2) {
          Cbf[idx] = f2bf(gelu_tanh(v + aux1[col]));
        } else {
          const float gg = aux2[(long)(rb + r) * 4];
          Cf[idx] += gg * (v + aux1[col]);
        }
      }
    }
  }
}

// ---------- V transpose: vt[bh][d][S] <- qkv V section ----------
__global__ __launch_bounds__(256) void vtrans_kernel(
    const bf16* __restrict__ qkv, bf16* __restrict__ vt)
{
  __shared__ short t[64][72];
  const int kt = blockIdx.x;   // S/64
  const int bh = blockIdx.y;   // B*H
  const int b = bh / HH, h = bh % HH;
  const int tid = threadIdx.x;
  const short* vg = (const short*)qkv + ((long)(b * SS + kt * 64)) * 2304 + 1536 + h * 64;
  #pragma unroll
  for (int i = 0; i < 2; i++) {
    const int idx = i * 256 + tid;
    const int r = idx >> 3, c = (idx & 7) * 8;
    *(bf16x8*)(&t[r][c]) = *(const bf16x8*)(vg + (long)r * 2304 + c);
  }
  __syncthreads();
  short* vo = (short*)vt + (long)bh * 64 * SS + kt * 64;
  #pragma unroll
  for (int i = 0; i < 2; i++) {
    const int idx = i * 256 + tid;
    const int d = idx >> 3, r0 = (idx & 7) * 8;
    bf16x8 o;
    #pragma unroll
    for (int j = 0; j < 8; j++) o[j] = t[r0 + j][d];
    *(bf16x8*)(vo + (long)d * SS + r0) = o;
  }
}

// ---------- MFMA flash attention: 4 waves x 16 q-rows, 64-kpos tiles --------
// LDS tiles are 128B rows -> XOR chunk-swizzle (chunk ^= row&7) everywhere;
// K/V staged via global_load_lds with pre-swizzled GLOBAL source (linear dest).
__global__ __launch_bounds__(256) void attn_kernel(
    const bf16* __restrict__ qkv, const bf16* __restrict__ vt,
    bf16* __restrict__ ctx)
{
  __shared__ __align__(16) short Qs[64 * 64];
  __shared__ __align__(16) short Ks[64 * 64];
  __shared__ __align__(16) short Vts[64 * 64];
  __shared__ __align__(16) short Ps[4][16 * 64];

  const int qt = blockIdx.x;      // 0..15
  const int bh = blockIdx.y;      // 0..47
  const int b = bh / HH, h = bh % HH;
  const int tid = threadIdx.x, lane = tid & 63, w = tid >> 6;
  const int lr = lane & 15, lg = lane >> 4;

  // ---- stage Q (scaled by 1/8), swizzled write ----
  const short* qg = (const short*)qkv + ((long)(b * SS + qt * 64)) * 2304 + h * 64;
  #pragma unroll
  for (int i = 0; i < 2; i++) {
    const int idx = i * 256 + tid;
    const int r = idx >> 3, c8 = idx & 7;
    bf16x8 v = *(const bf16x8*)(qg + (long)r * 2304 + c8 * 8);
    bf16x8 o;
    #pragma unroll
    for (int j = 0; j < 8; j++) o[j] = f2sb(sb2f(v[j]) * 0.125f);
    *(bf16x8*)(&Qs[r * 64 + ((c8 ^ (r & 7)) * 8)]) = o;
  }
  __syncthreads();

  // persistent Q fragments (A-frag: lane holds Q[q=lr][d=lg*8..+7 (+32)])
  bf16x8 aq[2];
  {
    const int r = w * 16 + lr;
    aq[0] = *(const bf16x8*)(&Qs[r * 64 + (((lg + 0) ^ (r & 7)) * 8)]);
    aq[1] = *(const bf16x8*)(&Qs[r * 64 + (((lg + 4) ^ (r & 7)) * 8)]);
  }

  float m_run[4], l_run[4];
  f32x4 oacc[4];
  #pragma unroll
  for (int r = 0; r < 4; r++) { m_run[r] = -1e30f; l_run[r] = 0.f; }
  #pragma unroll
  for (int dt = 0; dt < 4; dt++) oacc[dt] = (f32x4){0.f, 0.f, 0.f, 0.f};

  const short* kg = (const short*)qkv + ((long)(b * SS)) * 2304 + 768 + h * 64;
  const short* vg = (const short*)vt + ((long)bh * 64) * SS;
  const int sr = lane >> 3, sc = lane & 7;   // staging: 8 rows x 8 chunks / wave-call

  for (int kt = 0; kt < 16; kt++) {
    __syncthreads();
    #pragma unroll
    for (int c = 0; c < 2; c++) {
      const int rb = c * 32 + w * 8;
      const int row = rb + sr;
      const int ch = sc ^ (row & 7);            // pre-swizzled source chunk
      gld16(kg + ((long)(kt * 64 + row)) * 2304 + ch * 8, &Ks[rb * 64]);
      gld16(vg + ((long)row) * SS + kt * 64 + ch * 8, &Vts[rb * 64]);
    }
    __syncthreads();

    // QK^T: D[q][kpos], 4 col-tiles of 16 kpos
    f32x4 s[4];
    #pragma unroll
    for (int jt = 0; jt < 4; jt++) {
      const int r = jt * 16 + lr;
      bf16x8 bk0 = *(const bf16x8*)(&Ks[r * 64 + (((lg + 0) ^ (r & 7)) * 8)]);
      bf16x8 bk1 = *(const bf16x8*)(&Ks[r * 64 + (((lg + 4) ^ (r & 7)) * 8)]);
      f32x4 a = {};
      a = __builtin_amdgcn_mfma_f32_16x16x32_bf16(aq[0], bk0, a, 0, 0, 0);
      a = __builtin_amdgcn_mfma_f32_16x16x32_bf16(aq[1], bk1, a, 0, 0, 0);
      s[jt] = a;
    }

    // online softmax; lane owns q-rows lg*4+r, cols lr+16*jt
    #pragma unroll
    for (int r = 0; r < 4; r++) {
      float mt = fmaxf(fmaxf(s[0][r], s[1][r]), fmaxf(s[2][r], s[3][r]));
      mt = fmaxf(mt, __shfl_xor(mt, 1, 64));
      mt = fmaxf(mt, __shfl_xor(mt, 2, 64));
      mt = fmaxf(mt, __shfl_xor(mt, 4, 64));
      mt = fmaxf(mt, __shfl_xor(mt, 8, 64));
      const float mn = fmaxf(m_run[r], mt);
      const float sc0 = __expf(m_run[r] - mn);
      m_run[r] = mn;
      float p0 = __expf(s[0][r] - mn), p1 = __expf(s[1][r] - mn);
      float p2 = __expf(s[2][r] - mn), p3 = __expf(s[3][r] - mn);
      float rs = p0 + p1 + p2 + p3;
      rs += __shfl_xor(rs, 1, 64);
      rs += __shfl_xor(rs, 2, 64);
      rs += __shfl_xor(rs, 4, 64);
      rs += __shfl_xor(rs, 8, 64);
      l_run[r] = l_run[r] * sc0 + rs;
      #pragma unroll
      for (int dt = 0; dt < 4; dt++) oacc[dt][r] *= sc0;
      const int prow = lg * 4 + r;
      const int pswz = (prow & 7) << 3;
      Ps[w][prow * 64 + ((0 * 16 + lr) ^ pswz)] = f2sb(p0);
      Ps[w][prow * 64 + ((1 * 16 + lr) ^ pswz)] = f2sb(p1);
      Ps[w][prow * 64 + ((2 * 16 + lr) ^ pswz)] = f2sb(p2);
      Ps[w][prow * 64 + ((3 * 16 + lr) ^ pswz)] = f2sb(p3);
    }

    // PV: A-frag = P[q=lr][kpos=lg*8..+7 (+32)], B-frag = V via Vt rows
    bf16x8 pa0 = *(const bf16x8*)(&Ps[w][lr * 64 + (((lg + 0) ^ (lr & 7)) << 3)]);
    bf16x8 pa1 = *(const bf16x8*)(&Ps[w][lr * 64 + (((lg + 4) ^ (lr & 7)) << 3)]);
    #pragma unroll
    for (int dt = 0; dt < 4; dt++) {
      const int r = dt * 16 + lr;
      bf16x8 bv0 = *(const bf16x8*)(&Vts[r * 64 + (((lg + 0) ^ (r & 7)) * 8)]);
      bf16x8 bv1 = *(const bf16x8*)(&Vts[r * 64 + (((lg + 4) ^ (r & 7)) * 8)]);
      oacc[dt] = __builtin_amdgcn_mfma_f32_16x16x32_bf16(pa0, bv0, oacc[dt], 0, 0, 0);
      oacc[dt] = __builtin_amdgcn_mfma_f32_16x16x32_bf16(pa1, bv1, oacc[dt], 0, 0, 0);
    }
  }

  #pragma unroll
  for (int r = 0; r < 4; r++) {
    const float inv = 1.f / l_run[r];
    const long row = (long)(b * SS + qt * 64 + w * 16 + lg * 4 + r);
    #pragma unroll
    for (int dt = 0; dt < 4; dt++)
      ctx[row * DD + h * 64 + dt * 16 + lr] = f2bf(oacc[dt][r] * inv);
  }
}

// ---------- gate: exact-fp32 LN2 + logits + top2 softmax ----------
__global__ __launch_bounds__(256) void gate_kernel(
    const float* __restrict__ x2, const float* __restrict__ g,
    const float* __restrict__ bln, const float* __restrict__ Wg,
    const float* __restrict__ rbias, float* __restrict__ gates)
{
  const int t = blockIdx.x * 4 + (threadIdx.x >> 6);
  const int lane = threadIdx.x & 63;
  const int b = t >> 10;
  const float* xr = x2 + (long)t * DD;
  float v[12];
  float s = 0.f;
  #pragma unroll
  for (int i = 0; i < 12; i++) { v[i] = xr[lane + i * 64]; s += v[i]; }
  #pragma unroll
  for (int o = 1; o < 64; o <<= 1) s += __shfl_xor(s, o, 64);
  const float mu = s * (1.f / DD);
  float vs = 0.f;
  #pragma unroll
  for (int i = 0; i < 12; i++) { const float d = v[i] - mu; vs += d * d; }
  #pragma unroll
  for (int o = 1; o < 64; o <<= 1) vs += __shfl_xor(vs, o, 64);
  const float rstd = rsqrtf(vs * (1.f / DD) + 1e-5f);
  float a0 = 0.f, a1 = 0.f, a2 = 0.f, a3 = 0.f;
  #pragma unroll
  for (int i = 0; i < 12; i++) {
    const int d = lane + i * 64;
    const float hv = (v[i] - mu) * rstd * g[d] + bln[d];
    const f32x4 w = *(const f32x4*)(&Wg[d * 4]);
    a0 += hv * w.x; a1 += hv * w.y; a2 += hv * w.z; a3 += hv * w.w;
  }
  #pragma unroll
  for (int o = 1; o < 64; o <<= 1) {
    a0 += __shfl_xor(a0, o, 64); a1 += __shfl_xor(a1, o, 64);
    a2 += __shfl_xor(a2, o, 64); a3 += __shfl_xor(a3, o, 64);
  }
  if (lane == 0) {
    float lg[4] = { a0 + rbias[b * 4 + 0], a1 + rbias[b * 4 + 1],
                    a2 + rbias[b * 4 + 2], a3 + rbias[b * 4 + 3] };
    int i1 = 0;
    #pragma unroll
    for (int e = 1; e < 4; e++) if (lg[e] > lg[i1]) i1 = e;
    int i2 = -1;
    #pragma unroll
    for (int e = 0; e < 4; e++) if (e != i1 && (i2 < 0 || lg[e] > lg[i2])) i2 = e;
    const float e2 = __expf(lg[i2] - lg[i1]);
    const float den = 1.f + e2;
    float og[4] = {0.f, 0.f, 0.f, 0.f};
    og[i1] = 1.f / den;
    og[i2] = e2 / den;
    *(f32x4*)(&gates[t * 4]) = (f32x4){og[0], og[1], og[2], og[3]};
  }
}

__global__ __launch_bounds__(256) void copy4_kernel(
    const float* __restrict__ src, float* __restrict__ dst)
{
  const long i = ((long)blockIdx.x * 256 + threadIdx.x) * 4;
  *(f32x4*)(&dst[i]) = *(const f32x4*)(&src[i]);
}

extern "C" void kernel_launch(void* const* d_in, const int* in_sizes, int n_in,
                              void* d_out, int out_size, void* d_ws, size_t ws_size,
                              hipStream_t stream)
{
  (void)in_sizes; (void)n_in; (void)out_size; (void)ws_size;
  const float* x    = (const float*)d_in[0];
  const float* ln1g = (const float*)d_in[1];
  const float* ln1b = (const float*)d_in[2];
  const float* Wq   = (const float*)d_in[3];
  const float* Wk   = (const float*)d_in[4];
  const float* Wv   = (const float*)d_in[5];
  const float* Wo   = (const float*)d_in[6];
  const float* Wt   = (const float*)d_in[7];
  const float* bt   = (const float*)d_in[8];
  const float* ln2g = (const float*)d_in[9];
  const float* ln2b = (const float*)d_in[10];
  const float* Wg   = (const float*)d_in[11];
  const float* W1   = (const float*)d_in[12];
  const float* b1   = (const float*)d_in[13];
  const float* W2   = (const float*)d_in[14];
  const float* b2   = (const float*)d_in[15];
  float* out = (float*)d_out;

  char* ws = (char*)d_ws;
  bf16*  wqkv_t = (bf16*)(ws + 0);          // [2304][768] bf16
  bf16*  wo_t   = (bf16*)(ws + 3538944);    // [768][768]
  bf16*  w1t    = (bf16*)(ws + 4718592);    // [4][3072][768]
  bf16*  w2t    = (bf16*)(ws + 23592960);   // [4][768][3072]
  float* pooled = (float*)(ws + 42467328);  // [4][768]
  float* rbias  = (float*)(ws + 42479616);  // [4][4]
  bf16*  h1     = (bf16*)(ws + 42479872);   // [4096][768]  (dead after QKV gemm)
  bf16*  qkv    = (bf16*)(ws + 48771328);   // [4096][2304]
  bf16*  ctx    = (bf16*)(ws + 67645696);   // [4096][768]
  float* x2     = (float*)(ws + 73937152);  // [4096][768] f32
  bf16*  h2     = (bf16*)(ws + 86520064);   // [4096][768]
  float* gates  = (float*)(ws + 92811520);  // [4096][4] f32
  bf16*  hid    = qkv;                      // alias: qkv dead by MoE time
  bf16*  vt     = h1;                       // alias: [48][64][1024] = 6291456 B

  const dim3 tb(32, 8);
  transpose_cast_kernel<<<dim3(24, 24, 1), tb, 0, stream>>>(Wq, wqkv_t,           768, 768, 0, 0);
  transpose_cast_kernel<<<dim3(24, 24, 1), tb, 0, stream>>>(Wk, wqkv_t + 589824,  768, 768, 0, 0);
  transpose_cast_kernel<<<dim3(24, 24, 1), tb, 0, stream>>>(Wv, wqkv_t + 1179648, 768, 768, 0, 0);
  transpose_cast_kernel<<<dim3(24, 24, 1), tb, 0, stream>>>(Wo, wo_t,             768, 768, 0, 0);
  transpose_cast_kernel<<<dim3(96, 24, 4), tb, 0, stream>>>(W1, w1t, 768, 3072, 2359296, 2359296);
  transpose_cast_kernel<<<dim3(24, 96, 4), tb, 0, stream>>>(W2, w2t, 3072, 768, 2359296, 2359296);

  pool_kernel<<<12, 256, 0, stream>>>(x, pooled);
  route_kernel<<<1, 256, 0, stream>>>(pooled, Wt, bt, rbias);
  ln_kernel<<<1024, 256, 0, stream>>>(x, ln1g, ln1b, h1);

  gemm128_kernel<0><<<dim3(18, 32), 256, 0, stream>>>(h1, wqkv_t, qkv, nullptr,
                                                      4096, 2304, 768, nullptr, nullptr);
  vtrans_kernel<<<dim3(16, 48), 256, 0, stream>>>(qkv, vt);
  attn_kernel<<<dim3(16, 48), 256, 0, stream>>>(qkv, vt, ctx);
  gemm128_kernel<1><<<dim3(6, 32), 256, 0, stream>>>(ctx, wo_t, nullptr, x2,
                                                     4096, 768, 768, x, nullptr);
  ln_kernel<<<1024, 256, 0, stream>>>(x2, ln2g, ln2b, h2);
  gate_kernel<<<1024, 256, 0, stream>>>(x2, ln2g, ln2b, Wg, rbias, gates);
  copy4_kernel<<<3072, 256, 0, stream>>>(x2, out);

  for (int e = 0; e < 4; e++) {
    gemm128_kernel<2><<<dim3(24, 32), 256, 0, stream>>>(h2, w1t + (long)e * 2359296, hid, nullptr,
                                                        4096, 3072, 768, b1 + e * 3072, nullptr);
    gemm128_kernel<3><<<dim3(6, 32), 256, 0, stream>>>(hid, w2t + (long)e * 2359296, nullptr, out,
                                                       4096, 768, 3072, b2 + e * 768, gates + e);
  }
}

// Round 3
// 668.090 us; speedup vs baseline: 1.3771x; 1.0472x over previous
//
#include <hip/hip_runtime.h>
#include <hip/hip_bf16.h>

using bf16 = __hip_bfloat16;
typedef float f32x4 __attribute__((ext_vector_type(4)));
typedef short bf16x8 __attribute__((ext_vector_type(8)));

#define DD 768
#define SS 1024
#define HH 12
#define DFF 3072

__device__ __forceinline__ float bf2f(bf16 v) { return __bfloat162float(v); }
__device__ __forceinline__ bf16 f2bf(float v) { return __float2bfloat16(v); }
__device__ __forceinline__ float sb2f(short u) {
  return __uint_as_float(((unsigned)(unsigned short)u) << 16);
}
__device__ __forceinline__ short f2sb(float f) {
  bf16 b = f2bf(f);
  return reinterpret_cast<short&>(b);
}

// async global->LDS, 16B per lane; lds base must be wave-uniform
__device__ __forceinline__ void gld16(const void* g, void* l) {
  __builtin_amdgcn_global_load_lds(
      (const __attribute__((address_space(1))) void*)g,
      (__attribute__((address_space(3))) void*)l, 16, 0, 0);
}

// ---------- transpose + cast f32 -> bf16 : dst[c][r] = src[r][c] ----------
__global__ __launch_bounds__(256) void transpose_cast_kernel(
    const float* __restrict__ src, bf16* __restrict__ dst,
    int R, int C, long sstride, long dstride)
{
  __shared__ float tile[32][33];
  const int c0 = blockIdx.x * 32, r0 = blockIdx.y * 32;
  const float* s = src + (long)blockIdx.z * sstride;
  bf16* d = dst + (long)blockIdx.z * dstride;
  for (int i = threadIdx.y; i < 32; i += 8)
    tile[i][threadIdx.x] = s[(long)(r0 + i) * C + c0 + threadIdx.x];
  __syncthreads();
  for (int i = threadIdx.y; i < 32; i += 8)
    d[(long)(c0 + i) * R + r0 + threadIdx.x] = f2bf(tile[threadIdx.x][i]);
}

// ---------- pooled = mean over S ----------
__global__ __launch_bounds__(256) void pool_kernel(
    const float* __restrict__ x, float* __restrict__ pooled)
{
  const int idx = blockIdx.x * 256 + threadIdx.x;   // 0..3071  (B*D)
  const int b = idx / DD, d = idx % DD;
  const float* p = x + (long)b * SS * DD + d;
  float s = 0.f;
  for (int t = 0; t < SS; t++) s += p[(long)t * DD];
  pooled[idx] = s * (1.f / SS);
}

// ---------- routing bias ----------
__global__ __launch_bounds__(256) void route_kernel(
    const float* __restrict__ pooled, const float* __restrict__ Wt,
    const float* __restrict__ bt, float* __restrict__ rbias)
{
  __shared__ float tl[8];
  const int pair = threadIdx.x >> 5, l = threadIdx.x & 31;
  const int b = pair >> 1, j = pair & 1;
  float s = 0.f;
  for (int i = l; i < DD; i += 32) s += pooled[b * DD + i] * Wt[i * 2 + j];
  #pragma unroll
  for (int o = 1; o < 32; o <<= 1) s += __shfl_xor(s, o, 64);
  if (l == 0) tl[pair] = s + bt[j];
  __syncthreads();
  if (threadIdx.x < 16) {
    const int bb = threadIdx.x >> 2, e = threadIdx.x & 3;
    rbias[threadIdx.x] = tl[bb * 2 + (e & 1)];
  }
}

// ---------- layernorm row -> bf16 (wave per row) ----------
__global__ __launch_bounds__(256) void ln_kernel(
    const float* __restrict__ x, const float* __restrict__ g,
    const float* __restrict__ b, bf16* __restrict__ out)
{
  const int row = blockIdx.x * 4 + (threadIdx.x >> 6);
  const int lane = threadIdx.x & 63;
  const float* xr = x + (long)row * DD;
  float v[12];
  float s = 0.f;
  #pragma unroll
  for (int i = 0; i < 12; i++) { v[i] = xr[lane + i * 64]; s += v[i]; }
  #pragma unroll
  for (int o = 1; o < 64; o <<= 1) s += __shfl_xor(s, o, 64);
  const float mu = s * (1.f / DD);
  float vs = 0.f;
  #pragma unroll
  for (int i = 0; i < 12; i++) { const float d = v[i] - mu; vs += d * d; }
  #pragma unroll
  for (int o = 1; o < 64; o <<= 1) vs += __shfl_xor(vs, o, 64);
  const float rstd = rsqrtf(vs * (1.f / DD) + 1e-5f);
  bf16* orow = out + (long)row * DD;
  #pragma unroll
  for (int i = 0; i < 12; i++) {
    const int d = lane + i * 64;
    orow[d] = f2bf((v[i] - mu) * rstd * g[d] + b[d]);
  }
}

__device__ __forceinline__ float gelu_tanh(float x) {
  const float x3 = x * x * x;
  const float t = tanhf(0.7978845608028654f * (x + 0.044715f * x3));
  return 0.5f * x * (1.f + t);
}

// ---------- 128x128 bf16 MFMA GEMM, A[M][K] x Bt[N][K] ----------
// 3-buffer depth-2 global_load_lds pipeline, counted vmcnt, raw barriers,
// bijective XCD swizzle (1D grid), y-major block decomposition.
// MODE 0: C=bf16   1: Cf = aux1 + acc, Cf2 = same   2: Cbf = gelu(acc+aux1[col])
// MODE 3: Cf += aux2[row*4] * (acc + aux1[col])
template <int MODE>
__global__ __launch_bounds__(256) void gemm128_kernel(
    const bf16* __restrict__ A, const bf16* __restrict__ Bt,
    bf16* __restrict__ Cbf, float* __restrict__ Cf, float* __restrict__ Cf2,
    int N, int K, int NT, int GX,
    const float* __restrict__ aux1, const float* __restrict__ aux2)
{
  __shared__ __align__(16) bf16 As[3][128 * 32];
  __shared__ __align__(16) bf16 Bs[3][128 * 32];

  // bijective XCD swizzle (m204): orig -> contiguous chunk per XCD
  const int nwg = gridDim.x;
  const int orig = blockIdx.x;
  const int q = nwg >> 3, r = nwg & 7;
  const int xcd = orig & 7, sidx = orig >> 3;
  const int wgid = (xcd < r ? xcd * (q + 1) : r * (q + 1) + (xcd - r) * q) + sidx;
  const int m0 = (wgid / GX) * 128, n0 = (wgid % GX) * 128;

  const int tid = threadIdx.x;
  const int lane = tid & 63, wv = tid >> 6;
  const int wr = wv >> 1, wc = wv & 1;
  const int lrow = lane & 15, lk = lane >> 4;
  const int srow = lane >> 2, scb = (lane & 3) * 8;   // staging lane map

  f32x4 acc[4][4] = {};

#define STAGE(T, BUF)                                                      \
  {                                                                        \
    const int k0s = (T) * 32;                                              \
    _Pragma("unroll")                                                      \
    for (int u = 0; u < 2; u++) {                                          \
      const int rb = u * 64 + wv * 16;                                     \
      gld16(&A[(long)(m0 + rb + srow) * K + k0s + scb], &As[BUF][rb * 32]);\
      gld16(&Bt[(long)(n0 + rb + srow) * K + k0s + scb], &Bs[BUF][rb * 32]);\
    }                                                                      \
  }

  STAGE(0, 0)
  STAGE(1, 1)

  for (int t = 0; t < NT; t++) {
    const int buf = t % 3;
    // tile t's 4 loads are the oldest; allow the younger tile's 4 to fly
    if (t < NT - 1) asm volatile("s_waitcnt vmcnt(4)" ::: "memory");
    else            asm volatile("s_waitcnt vmcnt(0)" ::: "memory");
    __builtin_amdgcn_s_barrier();
    __builtin_amdgcn_sched_barrier(0);
    if (t + 2 < NT) STAGE(t + 2, (t + 2) % 3)

    bf16x8 af[4], bfr[4];
    #pragma unroll
    for (int i = 0; i < 4; i++) {
      af[i]  = *(const bf16x8*)(&As[buf][(wr * 64 + i * 16 + lrow) * 32 + lk * 8]);
      bfr[i] = *(const bf16x8*)(&Bs[buf][(wc * 64 + i * 16 + lrow) * 32 + lk * 8]);
    }
    #pragma unroll
    for (int i = 0; i < 4; i++)
      #pragma unroll
      for (int j = 0; j < 4; j++)
        acc[i][j] = __builtin_amdgcn_mfma_f32_16x16x32_bf16(af[i], bfr[j], acc[i][j], 0, 0, 0);
    __builtin_amdgcn_sched_barrier(0);
  }
#undef STAGE

  #pragma unroll
  for (int i = 0; i < 4; i++) {
    const int rb = m0 + wr * 64 + i * 16 + lk * 4;
    #pragma unroll
    for (int j = 0; j < 4; j++) {
      const int col = n0 + wc * 64 + j * 16 + lrow;
      #pragma unroll
      for (int r2 = 0; r2 < 4; r2++) {
        const long idx = (long)(rb + r2) * N + col;
        const float v = acc[i][j][r2];
        if (MODE == 0) {
          Cbf[idx] = f2bf(v);
        } else if (MODE == 1) {
          const float o = aux1[idx] + v;
          Cf[idx] = o;
          Cf2[idx] = o;
        } else if (MODE == 2) {
          Cbf[idx] = f2bf(gelu_tanh(v + aux1[col]));
        } else {
          const float gg = aux2[(long)(rb + r2) * 4];
          Cf[idx] += gg * (v + aux1[col]);
        }
      }
    }
  }
}

// ---------- V transpose: vt[bh][d][S] <- qkv V section ----------
__global__ __launch_bounds__(256) void vtrans_kernel(
    const bf16* __restrict__ qkv, bf16* __restrict__ vt)
{
  __shared__ short t[64][72];
  const int kt = blockIdx.x;   // S/64
  const int bh = blockIdx.y;   // B*H
  const int b = bh / HH, h = bh % HH;
  const int tid = threadIdx.x;
  const short* vg = (const short*)qkv + ((long)(b * SS + kt * 64)) * 2304 + 1536 + h * 64;
  #pragma unroll
  for (int i = 0; i < 2; i++) {
    const int idx = i * 256 + tid;
    const int r = idx >> 3, c = (idx & 7) * 8;
    *(bf16x8*)(&t[r][c]) = *(const bf16x8*)(vg + (long)r * 2304 + c);
  }
  __syncthreads();
  short* vo = (short*)vt + (long)bh * 64 * SS + kt * 64;
  #pragma unroll
  for (int i = 0; i < 2; i++) {
    const int idx = i * 256 + tid;
    const int d = idx >> 3, r0 = (idx & 7) * 8;
    bf16x8 o;
    #pragma unroll
    for (int j = 0; j < 8; j++) o[j] = t[r0 + j][d];
    *(bf16x8*)(vo + (long)d * SS + r0) = o;
  }
}

// ---------- MFMA flash attention: 4 waves x 16 q-rows, 64-kpos tiles --------
__global__ __launch_bounds__(256) void attn_kernel(
    const bf16* __restrict__ qkv, const bf16* __restrict__ vt,
    bf16* __restrict__ ctx)
{
  __shared__ __align__(16) short Qs[64 * 64];
  __shared__ __align__(16) short Ks[64 * 64];
  __shared__ __align__(16) short Vts[64 * 64];
  __shared__ __align__(16) short Ps[4][16 * 64];

  const int qt = blockIdx.x;      // 0..15
  const int bh = blockIdx.y;      // 0..47
  const int b = bh / HH, h = bh % HH;
  const int tid = threadIdx.x, lane = tid & 63, w = tid >> 6;
  const int lr = lane & 15, lg = lane >> 4;

  // ---- stage Q (scaled by 1/8), swizzled write ----
  const short* qg = (const short*)qkv + ((long)(b * SS + qt * 64)) * 2304 + h * 64;
  #pragma unroll
  for (int i = 0; i < 2; i++) {
    const int idx = i * 256 + tid;
    const int r = idx >> 3, c8 = idx & 7;
    bf16x8 v = *(const bf16x8*)(qg + (long)r * 2304 + c8 * 8);
    bf16x8 o;
    #pragma unroll
    for (int j = 0; j < 8; j++) o[j] = f2sb(sb2f(v[j]) * 0.125f);
    *(bf16x8*)(&Qs[r * 64 + ((c8 ^ (r & 7)) * 8)]) = o;
  }
  __syncthreads();

  bf16x8 aq[2];
  {
    const int r = w * 16 + lr;
    aq[0] = *(const bf16x8*)(&Qs[r * 64 + (((lg + 0) ^ (r & 7)) * 8)]);
    aq[1] = *(const bf16x8*)(&Qs[r * 64 + (((lg + 4) ^ (r & 7)) * 8)]);
  }

  float m_run[4], l_run[4];
  f32x4 oacc[4];
  #pragma unroll
  for (int r = 0; r < 4; r++) { m_run[r] = -1e30f; l_run[r] = 0.f; }
  #pragma unroll
  for (int dt = 0; dt < 4; dt++) oacc[dt] = (f32x4){0.f, 0.f, 0.f, 0.f};

  const short* kg = (const short*)qkv + ((long)(b * SS)) * 2304 + 768 + h * 64;
  const short* vg = (const short*)vt + ((long)bh * 64) * SS;
  const int sr = lane >> 3, sc = lane & 7;

  for (int kt = 0; kt < 16; kt++) {
    __syncthreads();
    #pragma unroll
    for (int c = 0; c < 2; c++) {
      const int rb = c * 32 + w * 8;
      const int row = rb + sr;
      const int ch = sc ^ (row & 7);
      gld16(kg + ((long)(kt * 64 + row)) * 2304 + ch * 8, &Ks[rb * 64]);
      gld16(vg + ((long)row) * SS + kt * 64 + ch * 8, &Vts[rb * 64]);
    }
    __syncthreads();

    f32x4 s[4];
    #pragma unroll
    for (int jt = 0; jt < 4; jt++) {
      const int r = jt * 16 + lr;
      bf16x8 bk0 = *(const bf16x8*)(&Ks[r * 64 + (((lg + 0) ^ (r & 7)) * 8)]);
      bf16x8 bk1 = *(const bf16x8*)(&Ks[r * 64 + (((lg + 4) ^ (r & 7)) * 8)]);
      f32x4 a = {};
      a = __builtin_amdgcn_mfma_f32_16x16x32_bf16(aq[0], bk0, a, 0, 0, 0);
      a = __builtin_amdgcn_mfma_f32_16x16x32_bf16(aq[1], bk1, a, 0, 0, 0);
      s[jt] = a;
    }

    #pragma unroll
    for (int r = 0; r < 4; r++) {
      float mt = fmaxf(fmaxf(s[0][r], s[1][r]), fmaxf(s[2][r], s[3][r]));
      mt = fmaxf(mt, __shfl_xor(mt, 1, 64));
      mt = fmaxf(mt, __shfl_xor(mt, 2, 64));
      mt = fmaxf(mt, __shfl_xor(mt, 4, 64));
      mt = fmaxf(mt, __shfl_xor(mt, 8, 64));
      const float mn = fmaxf(m_run[r], mt);
      const float sc0 = __expf(m_run[r] - mn);
      m_run[r] = mn;
      float p0 = __expf(s[0][r] - mn), p1 = __expf(s[1][r] - mn);
      float p2 = __expf(s[2][r] - mn), p3 = __expf(s[3][r] - mn);
      float rs = p0 + p1 + p2 + p3;
      rs += __shfl_xor(rs, 1, 64);
      rs += __shfl_xor(rs, 2, 64);
      rs += __shfl_xor(rs, 4, 64);
      rs += __shfl_xor(rs, 8, 64);
      l_run[r] = l_run[r] * sc0 + rs;
      #pragma unroll
      for (int dt = 0; dt < 4; dt++) oacc[dt][r] *= sc0;
      const int prow = lg * 4 + r;
      const int pswz = (prow & 7) << 3;
      Ps[w][prow * 64 + ((0 * 16 + lr) ^ pswz)] = f2sb(p0);
      Ps[w][prow * 64 + ((1 * 16 + lr) ^ pswz)] = f2sb(p1);
      Ps[w][prow * 64 + ((2 * 16 + lr) ^ pswz)] = f2sb(p2);
      Ps[w][prow * 64 + ((3 * 16 + lr) ^ pswz)] = f2sb(p3);
    }

    bf16x8 pa0 = *(const bf16x8*)(&Ps[w][lr * 64 + (((lg + 0) ^ (lr & 7)) << 3)]);
    bf16x8 pa1 = *(const bf16x8*)(&Ps[w][lr * 64 + (((lg + 4) ^ (lr & 7)) << 3)]);
    #pragma unroll
    for (int dt = 0; dt < 4; dt++) {
      const int r = dt * 16 + lr;
      bf16x8 bv0 = *(const bf16x8*)(&Vts[r * 64 + (((lg + 0) ^ (r & 7)) * 8)]);
      bf16x8 bv1 = *(const bf16x8*)(&Vts[r * 64 + (((lg + 4) ^ (r & 7)) * 8)]);
      oacc[dt] = __builtin_amdgcn_mfma_f32_16x16x32_bf16(pa0, bv0, oacc[dt], 0, 0, 0);
      oacc[dt] = __builtin_amdgcn_mfma_f32_16x16x32_bf16(pa1, bv1, oacc[dt], 0, 0, 0);
    }
  }

  #pragma unroll
  for (int r = 0; r < 4; r++) {
    const float inv = 1.f / l_run[r];
    const long row = (long)(b * SS + qt * 64 + w * 16 + lg * 4 + r);
    #pragma unroll
    for (int dt = 0; dt < 4; dt++)
      ctx[row * DD + h * 64 + dt * 16 + lr] = f2bf(oacc[dt][r] * inv);
  }
}

// ---------- gate: exact-fp32 LN2 + logits + top2 softmax ----------
__global__ __launch_bounds__(256) void gate_kernel(
    const float* __restrict__ x2, const float* __restrict__ g,
    const float* __restrict__ bln, const float* __restrict__ Wg,
    const float* __restrict__ rbias, float* __restrict__ gates)
{
  const int t = blockIdx.x * 4 + (threadIdx.x >> 6);
  const int lane = threadIdx.x & 63;
  const int b = t >> 10;
  const float* xr = x2 + (long)t * DD;
  float v[12];
  float s = 0.f;
  #pragma unroll
  for (int i = 0; i < 12; i++) { v[i] = xr[lane + i * 64]; s += v[i]; }
  #pragma unroll
  for (int o = 1; o < 64; o <<= 1) s += __shfl_xor(s, o, 64);
  const float mu = s * (1.f / DD);
  float vs = 0.f;
  #pragma unroll
  for (int i = 0; i < 12; i++) { const float d = v[i] - mu; vs += d * d; }
  #pragma unroll
  for (int o = 1; o < 64; o <<= 1) vs += __shfl_xor(vs, o, 64);
  const float rstd = rsqrtf(vs * (1.f / DD) + 1e-5f);
  float a0 = 0.f, a1 = 0.f, a2 = 0.f, a3 = 0.f;
  #pragma unroll
  for (int i = 0; i < 12; i++) {
    const int d = lane + i * 64;
    const float hv = (v[i] - mu) * rstd * g[d] + bln[d];
    const f32x4 w = *(const f32x4*)(&Wg[d * 4]);
    a0 += hv * w.x; a1 += hv * w.y; a2 += hv * w.z; a3 += hv * w.w;
  }
  #pragma unroll
  for (int o = 1; o < 64; o <<= 1) {
    a0 += __shfl_xor(a0, o, 64); a1 += __shfl_xor(a1, o, 64);
    a2 += __shfl_xor(a2, o, 64); a3 += __shfl_xor(a3, o, 64);
  }
  if (lane == 0) {
    float lg[4] = { a0 + rbias[b * 4 + 0], a1 + rbias[b * 4 + 1],
                    a2 + rbias[b * 4 + 2], a3 + rbias[b * 4 + 3] };
    int i1 = 0;
    #pragma unroll
    for (int e = 1; e < 4; e++) if (lg[e] > lg[i1]) i1 = e;
    int i2 = -1;
    #pragma unroll
    for (int e = 0; e < 4; e++) if (e != i1 && (i2 < 0 || lg[e] > lg[i2])) i2 = e;
    const float e2 = __expf(lg[i2] - lg[i1]);
    const float den = 1.f + e2;
    float og[4] = {0.f, 0.f, 0.f, 0.f};
    og[i1] = 1.f / den;
    og[i2] = e2 / den;
    *(f32x4*)(&gates[t * 4]) = (f32x4){og[0], og[1], og[2], og[3]};
  }
}

extern "C" void kernel_launch(void* const* d_in, const int* in_sizes, int n_in,
                              void* d_out, int out_size, void* d_ws, size_t ws_size,
                              hipStream_t stream)
{
  (void)in_sizes; (void)n_in; (void)out_size; (void)ws_size;
  const float* x    = (const float*)d_in[0];
  const float* ln1g = (const float*)d_in[1];
  const float* ln1b = (const float*)d_in[2];
  const float* Wq   = (const float*)d_in[3];
  const float* Wk   = (const float*)d_in[4];
  const float* Wv   = (const float*)d_in[5];
  const float* Wo   = (const float*)d_in[6];
  const float* Wt   = (const float*)d_in[7];
  const float* bt   = (const float*)d_in[8];
  const float* ln2g = (const float*)d_in[9];
  const float* ln2b = (const float*)d_in[10];
  const float* Wg   = (const float*)d_in[11];
  const float* W1   = (const float*)d_in[12];
  const float* b1   = (const float*)d_in[13];
  const float* W2   = (const float*)d_in[14];
  const float* b2   = (const float*)d_in[15];
  float* out = (float*)d_out;

  char* ws = (char*)d_ws;
  bf16*  wqkv_t = (bf16*)(ws + 0);          // [2304][768] bf16
  bf16*  wo_t   = (bf16*)(ws + 3538944);    // [768][768]
  bf16*  w1t    = (bf16*)(ws + 4718592);    // [4][3072][768]
  bf16*  w2t    = (bf16*)(ws + 23592960);   // [4][768][3072]
  float* pooled = (float*)(ws + 42467328);  // [4][768]
  float* rbias  = (float*)(ws + 42479616);  // [4][4]
  bf16*  h1     = (bf16*)(ws + 42479872);   // [4096][768]  (dead after QKV gemm)
  bf16*  qkv    = (bf16*)(ws + 48771328);   // [4096][2304]
  bf16*  ctx    = (bf16*)(ws + 67645696);   // [4096][768]
  float* x2     = (float*)(ws + 73937152);  // [4096][768] f32
  bf16*  h2     = (bf16*)(ws + 86520064);   // [4096][768]
  float* gates  = (float*)(ws + 92811520);  // [4096][4] f32
  bf16*  hid    = qkv;                      // alias: qkv+ctx dead by MoE time
  bf16*  vt     = h1;                       // alias: [48][64][1024]

  const dim3 tb(32, 8);
  transpose_cast_kernel<<<dim3(24, 24, 1), tb, 0, stream>>>(Wq, wqkv_t,           768, 768, 0, 0);
  transpose_cast_kernel<<<dim3(24, 24, 1), tb, 0, stream>>>(Wk, wqkv_t + 589824,  768, 768, 0, 0);
  transpose_cast_kernel<<<dim3(24, 24, 1), tb, 0, stream>>>(Wv, wqkv_t + 1179648, 768, 768, 0, 0);
  transpose_cast_kernel<<<dim3(24, 24, 1), tb, 0, stream>>>(Wo, wo_t,             768, 768, 0, 0);
  transpose_cast_kernel<<<dim3(96, 24, 4), tb, 0, stream>>>(W1, w1t, 768, 3072, 2359296, 2359296);
  transpose_cast_kernel<<<dim3(24, 96, 4), tb, 0, stream>>>(W2, w2t, 3072, 768, 2359296, 2359296);

  pool_kernel<<<12, 256, 0, stream>>>(x, pooled);
  route_kernel<<<1, 256, 0, stream>>>(pooled, Wt, bt, rbias);
  ln_kernel<<<1024, 256, 0, stream>>>(x, ln1g, ln1b, h1);

  // QKV: M=4096 N=2304 K=768 -> grid 18*32
  gemm128_kernel<0><<<18 * 32, 256, 0, stream>>>(h1, wqkv_t, qkv, nullptr, nullptr,
                                                 2304, 768, 24, 18, nullptr, nullptr);
  vtrans_kernel<<<dim3(16, 48), 256, 0, stream>>>(qkv, vt);
  attn_kernel<<<dim3(16, 48), 256, 0, stream>>>(qkv, vt, ctx);
  // Wo + residual -> x2 and out
  gemm128_kernel<1><<<6 * 32, 256, 0, stream>>>(ctx, wo_t, nullptr, x2, out,
                                                768, 768, 24, 6, x, nullptr);
  ln_kernel<<<1024, 256, 0, stream>>>(x2, ln2g, ln2b, h2);
  gate_kernel<<<1024, 256, 0, stream>>>(x2, ln2g, ln2b, Wg, rbias, gates);

  for (int e = 0; e < 4; e++) {
    gemm128_kernel<2><<<24 * 32, 256, 0, stream>>>(h2, w1t + (long)e * 2359296, hid, nullptr, nullptr,
                                                   3072, 768, 24, 24, b1 + e * 3072, nullptr);
    gemm128_kernel<3><<<6 * 32, 256, 0, stream>>>(hid, w2t + (long)e * 2359296, nullptr, out, nullptr,
                                                  768, 3072, 96, 6, b2 + e * 768, gates + e);
  }
}